// Round 2
// baseline (208.142 us; speedup 1.0000x reference)
//
#include <hip/hip_runtime.h>
#include <stdint.h>

typedef short bf16x8 __attribute__((ext_vector_type(8)));
typedef float f32x4 __attribute__((ext_vector_type(4)));

__device__ __forceinline__ unsigned short f2bf(float f) {
  unsigned u = __float_as_uint(f);
  u += 0x7fffu + ((u >> 16) & 1u);
  return (unsigned short)(u >> 16);
}

// async global->LDS, 16B per lane; LDS dest = waveBase + lane*16 (call sites
// pass &buf[t*8], t = wid*64+lane -> consistent).
__device__ __forceinline__ void gld16(const ushort* g, ushort* l) {
  __builtin_amdgcn_global_load_lds(
      (__attribute__((address_space(1))) void*)g,
      (__attribute__((address_space(3))) void*)l, 16, 0, 0);
}

// ---------------- prep kernels ----------------
__global__ __launch_bounds__(256) void k_cast_bf16(const float* __restrict__ in,
                                                   ushort* __restrict__ out) {
  int i = (blockIdx.x * 256 + threadIdx.x) * 8;
  float4 a = *(const float4*)(in + i);
  float4 b = *(const float4*)(in + i + 4);
  union { ushort u[8]; uint4 q; } r;
  r.u[0] = f2bf(a.x); r.u[1] = f2bf(a.y); r.u[2] = f2bf(a.z); r.u[3] = f2bf(a.w);
  r.u[4] = f2bf(b.x); r.u[5] = f2bf(b.y); r.u[6] = f2bf(b.z); r.u[7] = f2bf(b.w);
  *(uint4*)(out + i) = r.q;
}

// fp32 [R][C] -> bf16 [C][R]
__global__ __launch_bounds__(256) void k_transpose_cast(const float* __restrict__ in,
                                                        ushort* __restrict__ out,
                                                        int R, int C) {
  __shared__ float tl[32][33];
  int t = threadIdx.x;
  {
    int r = t >> 3, c4 = (t & 7) * 4;
    float4 v = *(const float4*)(in + (size_t)(blockIdx.y * 32 + r) * C + blockIdx.x * 32 + c4);
    tl[r][c4] = v.x; tl[r][c4 + 1] = v.y; tl[r][c4 + 2] = v.z; tl[r][c4 + 3] = v.w;
  }
  __syncthreads();
  {
    int c = t >> 3, r4 = (t & 7) * 4;
    union { ushort u[4]; uint2 q; } o;
    o.u[0] = f2bf(tl[r4][c]);     o.u[1] = f2bf(tl[r4 + 1][c]);
    o.u[2] = f2bf(tl[r4 + 2][c]); o.u[3] = f2bf(tl[r4 + 3][c]);
    *(uint2*)(out + (size_t)(blockIdx.x * 32 + c) * R + blockIdx.y * 32 + r4) = o.q;
  }
}

// V [bh][2048][64] -> Vt [bh][64][2048]
__global__ __launch_bounds__(256) void k_vtrans(const ushort* __restrict__ V,
                                                ushort* __restrict__ Vt) {
  __shared__ ushort tl[64 * 72];
  int t = threadIdx.x;
  const ushort* inp = V + (size_t)blockIdx.y * 131072 + blockIdx.x * 4096;
#pragma unroll
  for (int p = 0; p < 2; ++p) {
    int r = (t >> 3) + p * 32, c8 = (t & 7) * 8;
    *(uint4*)&tl[r * 72 + c8] = *(const uint4*)&inp[r * 64 + c8];
  }
  __syncthreads();
  ushort* outp = Vt + (size_t)blockIdx.y * 131072 + blockIdx.x * 64;
#pragma unroll
  for (int p = 0; p < 2; ++p) {
    int d = (t >> 3) + p * 32, s8 = (t & 7) * 8;
    union { ushort u[8]; uint4 q; } o;
#pragma unroll
    for (int j = 0; j < 8; ++j) o.u[j] = tl[(s8 + j) * 72 + d];
    *(uint4*)&outp[d * 2048 + s8] = o.q;
  }
}

// ---------------- GEMM: A[M][1024] bf16 x Bt[N][1024] bf16 ----------------
// m97-verified pattern: LINEAR LDS (no swizzle) + global_load_lds width 16.
// 128x128 tile, BK=32, 4 waves (2x2), each wave 64x64 (4x4 of 16x16 frags).
template <int MODE>
__global__ __launch_bounds__(256, 2) void k_gemm(
    const ushort* __restrict__ A, const ushort* __restrict__ Bt,
    const float* __restrict__ bias, ushort* __restrict__ Q,
    ushort* __restrict__ Ko, ushort* __restrict__ V, float* __restrict__ Out) {
  __shared__ ushort As[128 * 32];
  __shared__ ushort Bs[128 * 32];
  const int t = threadIdx.x;
  const int lane = t & 63, wid = t >> 6;
  const int wr = wid >> 1, wc = wid & 1;
  const int rt = blockIdx.y, ct = blockIdx.x;

  // thread t covers LDS ushorts [t*8, t*8+8) = row (t>>2), k-group (t&3); linear.
  const int srow = t >> 2, sslot = t & 3;
  const ushort* ga = A + (size_t)(rt * 128 + srow) * 1024 + sslot * 8;
  const ushort* gb = Bt + (size_t)(ct * 128 + srow) * 1024 + sslot * 8;
  ushort* lA = &As[t * 8];
  ushort* lB = &Bs[t * 8];

  f32x4 acc[4][4];
#pragma unroll
  for (int m = 0; m < 4; ++m)
#pragma unroll
    for (int n = 0; n < 4; ++n) acc[m][n] = (f32x4){0.f, 0.f, 0.f, 0.f};

  int aidx[4], bidx[4];
#pragma unroll
  for (int m = 0; m < 4; ++m) {
    int ra = wr * 64 + m * 16 + (lane & 15);
    aidx[m] = ra * 32 + ((lane >> 4) << 3);
    int rb = wc * 64 + m * 16 + (lane & 15);
    bidx[m] = rb * 32 + ((lane >> 4) << 3);
  }

  gld16(ga, lA); gld16(ga + 65536, lA + 2048);
  gld16(gb, lB); gld16(gb + 65536, lB + 2048);

  for (int kt = 0; kt < 32; ++kt) {
    __syncthreads();
    bf16x8 af[4], bfv[4];
#pragma unroll
    for (int m = 0; m < 4; ++m) af[m] = *(const bf16x8*)&As[aidx[m]];
#pragma unroll
    for (int n = 0; n < 4; ++n) bfv[n] = *(const bf16x8*)&Bs[bidx[n]];
    __syncthreads();
    if (kt < 31) {
      const ushort* ga2 = ga + (kt + 1) * 32;
      const ushort* gb2 = gb + (kt + 1) * 32;
      gld16(ga2, lA); gld16(ga2 + 65536, lA + 2048);
      gld16(gb2, lB); gld16(gb2 + 65536, lB + 2048);
    }
#pragma unroll
    for (int m = 0; m < 4; ++m)
#pragma unroll
      for (int n = 0; n < 4; ++n)
        acc[m][n] = __builtin_amdgcn_mfma_f32_16x16x32_bf16(af[m], bfv[n], acc[m][n], 0, 0, 0);
  }

  const int colb = ct * 128 + wc * 64;
  const int rowb = rt * 128 + wr * 64;
  if constexpr (MODE == 0) {
#pragma unroll
    for (int n = 0; n < 4; ++n) {
      int col = colb + n * 16 + (lane & 15);
      float bv = bias[col];
      int three = col >> 10, hx = (col >> 6) & 15, d = col & 63;
      ushort* dst = (three == 0) ? Q : (three == 1) ? Ko : V;
#pragma unroll
      for (int m = 0; m < 4; ++m) {
        int r0 = rowb + m * 16 + ((lane >> 4) << 2);
#pragma unroll
        for (int r = 0; r < 4; ++r) {
          int row = r0 + r;
          int b = row >> 11, s = row & 2047;
          dst[(size_t)((b * 16 + hx) * 2048 + s) * 64 + d] = f2bf(acc[m][n][r] + bv);
        }
      }
    }
  } else {
#pragma unroll
    for (int n = 0; n < 4; ++n) {
      int col = colb + n * 16 + (lane & 15);
      float bv = bias[col];
#pragma unroll
      for (int m = 0; m < 4; ++m) {
        int r0 = rowb + m * 16 + ((lane >> 4) << 2);
#pragma unroll
        for (int r = 0; r < 4; ++r)
          Out[(size_t)(r0 + r) * 1024 + col] = acc[m][n][r] + bv;
      }
    }
  }
}

// ---------------- flash attention ----------------
// grid (16 q-tiles, 32 bh). 4 waves, each owns 32 q rows; Q frags in regs.
// K tile [64 s][72] and Vt tile [64 d][72]: REGISTER-staged (uint4 loads +
// ds_write_b128), +8-padded rows -> conflict-free, no swizzle. Next-tile reg
// loads issued before compute (overlap). Explicit barrier between P-write
// and PV-read removes the same-wave LDS-ordering assumption.
__global__ __launch_bounds__(256, 2) void k_attn(const ushort* __restrict__ Qb,
                                                 const ushort* __restrict__ Kb,
                                                 const ushort* __restrict__ Vtb,
                                                 ushort* __restrict__ AO) {
  __shared__ ushort Ks[64 * 72];
  __shared__ ushort Vs[64 * 72];
  __shared__ ushort Ps[128 * 72];
  const int t = threadIdx.x, lane = t & 63, wid = t >> 6;
  const int bh = blockIdx.y, qt = blockIdx.x;
  const ushort* Qh = Qb + (size_t)bh * 131072;
  const ushort* Kh = Kb + (size_t)bh * 131072;
  const ushort* Vh = Vtb + (size_t)bh * 131072;

  bf16x8 qf[2][2];
#pragma unroll
  for (int m = 0; m < 2; ++m)
#pragma unroll
    for (int kk = 0; kk < 2; ++kk) {
      int row = qt * 128 + wid * 32 + m * 16 + (lane & 15);
      int k = kk * 32 + ((lane >> 4) << 3);
      qf[m][kk] = *(const bf16x8*)&Qh[row * 64 + k];
    }

  f32x4 oacc[2][4];
  float mrow[2][4], lrow[2][4];
#pragma unroll
  for (int m = 0; m < 2; ++m) {
#pragma unroll
    for (int n = 0; n < 4; ++n) oacc[m][n] = (f32x4){0.f, 0.f, 0.f, 0.f};
#pragma unroll
    for (int r = 0; r < 4; ++r) { mrow[m][r] = -1e30f; lrow[m][r] = 0.f; }
  }

  // staging geometry: chunk c = t + p*256 -> row (c>>3) in [0,64), slot (c&7)
  const int strow = t >> 3, stslot = (t & 7) * 8;

  int kidx[4][2];
#pragma unroll
  for (int n = 0; n < 4; ++n)
#pragma unroll
    for (int kk = 0; kk < 2; ++kk) {
      int row = n * 16 + (lane & 15);
      int g = kk * 4 + (lane >> 4);
      kidx[n][kk] = row * 72 + (g << 3);
    }
  int pridx[2][2];
#pragma unroll
  for (int m = 0; m < 2; ++m)
#pragma unroll
    for (int kk = 0; kk < 2; ++kk)
      pridx[m][kk] = (wid * 32 + m * 16 + (lane & 15)) * 72 + kk * 32 + ((lane >> 4) << 3);

  uint4 kreg[2], vreg[2];
#pragma unroll
  for (int p = 0; p < 2; ++p) {
    int row = strow + p * 32;
    kreg[p] = *(const uint4*)&Kh[(size_t)row * 64 + stslot];
    vreg[p] = *(const uint4*)&Vh[(size_t)row * 2048 + stslot];
  }

  for (int kt = 0; kt < 32; ++kt) {
    __syncthreads();  // all PV reads of previous tile done
#pragma unroll
    for (int p = 0; p < 2; ++p) {
      int row = strow + p * 32;
      *(uint4*)&Ks[row * 72 + stslot] = kreg[p];
      *(uint4*)&Vs[row * 72 + stslot] = vreg[p];
    }
    __syncthreads();  // tiles ready
    if (kt < 31) {    // overlap next-tile loads with compute
#pragma unroll
      for (int p = 0; p < 2; ++p) {
        int row = strow + p * 32;
        kreg[p] = *(const uint4*)&Kh[(size_t)((kt + 1) * 64 + row) * 64 + stslot];
        vreg[p] = *(const uint4*)&Vh[(size_t)row * 2048 + (kt + 1) * 64 + stslot];
      }
    }
    f32x4 sacc[2][4];
#pragma unroll
    for (int m = 0; m < 2; ++m)
#pragma unroll
      for (int n = 0; n < 4; ++n) sacc[m][n] = (f32x4){0.f, 0.f, 0.f, 0.f};
#pragma unroll
    for (int kk = 0; kk < 2; ++kk) {
      bf16x8 kf[4];
#pragma unroll
      for (int n = 0; n < 4; ++n) kf[n] = *(const bf16x8*)&Ks[kidx[n][kk]];
#pragma unroll
      for (int m = 0; m < 2; ++m)
#pragma unroll
        for (int n = 0; n < 4; ++n)
          sacc[m][n] = __builtin_amdgcn_mfma_f32_16x16x32_bf16(qf[m][kk], kf[n], sacc[m][n], 0, 0, 0);
    }
    // online softmax; row (lane>>4)*4+r of each 16-block lives in a 16-lane group
#pragma unroll
    for (int m = 0; m < 2; ++m) {
#pragma unroll
      for (int r = 0; r < 4; ++r) {
        float s0 = sacc[m][0][r] * 0.125f;
        float s1 = sacc[m][1][r] * 0.125f;
        float s2 = sacc[m][2][r] * 0.125f;
        float s3 = sacc[m][3][r] * 0.125f;
        float mx = fmaxf(fmaxf(s0, s1), fmaxf(s2, s3));
#pragma unroll
        for (int off = 1; off < 16; off <<= 1) mx = fmaxf(mx, __shfl_xor(mx, off));
        float mo = mrow[m][r];
        float mn = fmaxf(mo, mx);
        float corr = __expf(mo - mn);
        mrow[m][r] = mn;
        float p0 = __expf(s0 - mn), p1 = __expf(s1 - mn);
        float p2 = __expf(s2 - mn), p3 = __expf(s3 - mn);
        float ss = p0 + p1 + p2 + p3;
#pragma unroll
        for (int off = 1; off < 16; off <<= 1) ss += __shfl_xor(ss, off);
        lrow[m][r] = lrow[m][r] * corr + ss;
#pragma unroll
        for (int n = 0; n < 4; ++n) oacc[m][n][r] *= corr;
        int q = wid * 32 + m * 16 + ((lane >> 4) << 2) + r;
        int pb = q * 72 + (lane & 15);
        Ps[pb] = f2bf(p0); Ps[pb + 16] = f2bf(p1);
        Ps[pb + 32] = f2bf(p2); Ps[pb + 48] = f2bf(p3);
      }
    }
    __syncthreads();  // P visible (block-level guarantee, removes same-wave assumption)
    // PV
#pragma unroll
    for (int kk = 0; kk < 2; ++kk) {
      bf16x8 pa[2];
#pragma unroll
      for (int m = 0; m < 2; ++m) pa[m] = *(const bf16x8*)&Ps[pridx[m][kk]];
#pragma unroll
      for (int nd = 0; nd < 4; ++nd) {
        bf16x8 vf = *(const bf16x8*)&Vs[kidx[nd][kk]];
#pragma unroll
        for (int m = 0; m < 2; ++m)
          oacc[m][nd] = __builtin_amdgcn_mfma_f32_16x16x32_bf16(pa[m], vf, oacc[m][nd], 0, 0, 0);
      }
    }
  }

  const int b = bh >> 4, h = bh & 15;
#pragma unroll
  for (int m = 0; m < 2; ++m) {
    float inv[4];
#pragma unroll
    for (int r = 0; r < 4; ++r) inv[r] = 1.0f / lrow[m][r];
#pragma unroll
    for (int nd = 0; nd < 4; ++nd) {
      int d = nd * 16 + (lane & 15);
#pragma unroll
      for (int r = 0; r < 4; ++r) {
        int s = qt * 128 + wid * 32 + m * 16 + ((lane >> 4) << 2) + r;
        AO[(size_t)((b * 2048 + s) * 16 + h) * 64 + d] = f2bf(oacc[m][nd][r] * inv[r]);
      }
    }
  }
}

extern "C" void kernel_launch(void* const* d_in, const int* in_sizes, int n_in,
                              void* d_out, int out_size, void* d_ws, size_t ws_size,
                              hipStream_t stream) {
  const float* x = (const float*)d_in[0];
  const float* w_qkv = (const float*)d_in[1];
  const float* b_qkv = (const float*)d_in[2];
  const float* w_out = (const float*)d_in[3];
  const float* b_out = (const float*)d_in[4];
  float* out = (float*)d_out;

  char* p = (char*)d_ws;
  ushort* xb = (ushort*)p;    p += (size_t)4096 * 1024 * 2;   // reused as AO later
  ushort* wqkvT = (ushort*)p; p += (size_t)3072 * 1024 * 2;
  ushort* woutT = (ushort*)p; p += (size_t)1024 * 1024 * 2;
  ushort* Qb = (ushort*)p;    p += (size_t)32 * 2048 * 64 * 2;
  ushort* Kb = (ushort*)p;    p += (size_t)32 * 2048 * 64 * 2;
  ushort* Vb = (ushort*)p;    p += (size_t)32 * 2048 * 64 * 2;
  ushort* Vtb = (ushort*)p;   p += (size_t)32 * 2048 * 64 * 2;
  ushort* AO = xb;  // xb dead after QKV GEMM; reuse (stream-ordered, safe)

  k_cast_bf16<<<2048, 256, 0, stream>>>(x, xb);
  k_transpose_cast<<<dim3(96, 32), 256, 0, stream>>>(w_qkv, wqkvT, 1024, 3072);
  k_transpose_cast<<<dim3(32, 32), 256, 0, stream>>>(w_out, woutT, 1024, 1024);
  k_gemm<0><<<dim3(24, 32), 256, 0, stream>>>(xb, wqkvT, b_qkv, Qb, Kb, Vb, nullptr);
  k_vtrans<<<dim3(32, 32), 256, 0, stream>>>(Vb, Vtb);
  k_attn<<<dim3(16, 32), 256, 0, stream>>>(Qb, Kb, Vtb, AO);
  k_gemm<1><<<dim3(8, 32), 256, 0, stream>>>(AO, woutT, b_out, nullptr, nullptr, nullptr, out);
}